// Round 8
// baseline (5425.149 us; speedup 1.0000x reference)
//
#include <hip/hip_runtime.h>
#include <math.h>

// Sizes (fixed by the problem)
#define BATCH   64
#define SEQ     512
#define NIN     512
#define NHID    1024
#define NOUT    512

// ---------------- Tiled fp32 GEMM with bias: C[M,N] = A[M,K] @ B[K,N] + bias[N]
// BM=128, BN=64, BK=16, 256 threads, 8x4 microtile.
#define BM 128
#define BN 64
#define BK 16

__global__ __launch_bounds__(256) void gemm_bias(
    const float* __restrict__ A, const float* __restrict__ B,
    const float* __restrict__ bias, float* __restrict__ C,
    int M, int N, int K) {
  __shared__ float As[BK][BM + 4];  // transposed A tile
  __shared__ float Bs[BK][BN + 4];

  const int tid = threadIdx.x;
  const int bx = blockIdx.x;  // N tile
  const int by = blockIdx.y;  // M tile

  const int tm = (tid / 16) * 8;   // 0..120, 8 rows
  const int tn = (tid % 16) * 4;   // 0..60, 4 cols

  const int ar = tid / 4;            // 0..63 (+64 second row)
  const int ac = (tid % 4) * 4;      // k 0,4,8,12
  const int br = tid / 16;           // 0..15
  const int bc = (tid % 16) * 4;     // 0..60

  float acc[8][4] = {};

  for (int k0 = 0; k0 < K; k0 += BK) {
    float4 av0 = *(const float4*)&A[(size_t)(by * BM + ar) * K + k0 + ac];
    float4 av1 = *(const float4*)&A[(size_t)(by * BM + ar + 64) * K + k0 + ac];
    As[ac + 0][ar] = av0.x;  As[ac + 0][ar + 64] = av1.x;
    As[ac + 1][ar] = av0.y;  As[ac + 1][ar + 64] = av1.y;
    As[ac + 2][ar] = av0.z;  As[ac + 2][ar + 64] = av1.z;
    As[ac + 3][ar] = av0.w;  As[ac + 3][ar + 64] = av1.w;
    float4 bv = *(const float4*)&B[(size_t)(k0 + br) * N + bx * BN + bc];
    *(float4*)&Bs[br][bc] = bv;
    __syncthreads();

#pragma unroll
    for (int k = 0; k < BK; ++k) {
      float4 a0 = *(const float4*)&As[k][tm];
      float4 a1 = *(const float4*)&As[k][tm + 4];
      float4 b4 = *(const float4*)&Bs[k][tn];
      float ae[8] = {a0.x, a0.y, a0.z, a0.w, a1.x, a1.y, a1.z, a1.w};
      float be[4] = {b4.x, b4.y, b4.z, b4.w};
#pragma unroll
      for (int i = 0; i < 8; ++i)
#pragma unroll
        for (int j = 0; j < 4; ++j)
          acc[i][j] = fmaf(ae[i], be[j], acc[i][j]);
    }
    __syncthreads();
  }

  const float4 bb = *(const float4*)&bias[bx * BN + tn];
#pragma unroll
  for (int i = 0; i < 8; ++i) {
    float4 o;
    o.x = acc[i][0] + bb.x;
    o.y = acc[i][1] + bb.y;
    o.z = acc[i][2] + bb.z;
    o.w = acc[i][3] + bb.w;
    *(float4*)&C[(size_t)(by * BM + tm + i) * N + bx * BN + tn] = o;
  }
}

// ---------------- Cooperative weight-stationary scan, v8 ----------------
// = v7 + L2-local sync fast path with MALL fallback:
//  - h and flags DUAL-stored: agent-scope atomic (MALL ground truth) then
//    plain store (fast copy in the XCD-shared L2 when the group is
//    co-located, which r7's FETCH drop confirmed).
//  - pollers spin with sc0 loads (L1-bypass, L2-hit ~200cy); every 8th
//    iteration escalates to sc0+sc1 (MALL truth) -> correct and
//    deadlock-free even if block->XCD mapping changes (flags monotonic).
//  - staging loads are plain: address is fresh each step and never cached
//    pre-finalization (xin stays a bypassing atomic), so any cached copy is
//    a finalized value; L2-miss fills from MALL which has the agent copy.
//  - next-step xin load hoisted before the poll (latency hidden).
#define GROUPS 8
#define BPG    32   // blocks per group (column chunks)
#define BPERG  8    // batches per group

#define FMA4(hv, wv4, accv)              \
  accv.x = fmaf(hv, wv4.x, accv.x);      \
  accv.y = fmaf(hv, wv4.y, accv.y);      \
  accv.z = fmaf(hv, wv4.z, accv.z);      \
  accv.w = fmaf(hv, wv4.w, accv.w);

__global__ __launch_bounds__(256, 1) void rnn_scan_ws(
    const float* __restrict__ Wh, float* __restrict__ xi,
    unsigned int* flags) {
  __shared__ float hs[BPERG * NHID];   // 32 KB staged h, XOR-swizzled on k
  __shared__ float P[256 * 32];        // 32 KB partial sums

  const int tid  = threadIdx.x;
  const int bg   = blockIdx.x & 7;    // XCD id under round-robin dispatch
  const int jc   = blockIdx.x >> 3;   // 0..31 column chunk (32 cols)
  const int c4   = tid & 7;           // column quad within chunk
  const int kseg = tid >> 3;          // 0..31 k-slice (32 k each)
  const int colbase = jc * 32 + c4 * 4;
  const int hswz  = (kseg & 7) << 2;        // read-side LDS swizzle (k bits 5-7)
  const int stswz = ((tid >> 3) & 7) << 2;  // write-side swizzle
  const int ob   = tid >> 5;          // output batch (0..7)
  const int ocol = tid & 31;          // output col within chunk
  const int oc4  = ocol >> 2;
  const int oce  = ocol & 3;

  // Wh sliver in registers: 32 float4 vector loads, fully unrolled.
  float4 w[32];
#pragma unroll
  for (int kk = 0; kk < 32; ++kk)
    w[kk] = *(const float4*)&Wh[(size_t)(kseg * 32 + kk) * NHID + colbase];

  // This thread's xi/h column pointer.
  float* const xrow_base =
      xi + (size_t)(bg * BPERG + ob) * SEQ * NHID + jc * 32 + ocol;
  // Per-group flag region: 32 uints (128B), regions disjoint per group.
  unsigned int* const gflags = flags + bg * 32;
  unsigned int* const myflag = gflags + jc;
  unsigned int* const pollflag = gflags + (tid & 31);

  // xin for step 0 (pre-activation line: bypassing load, never cached).
  float xin = __hip_atomic_load(xrow_base, __ATOMIC_RELAXED,
                                __HIP_MEMORY_SCOPE_AGENT);

  for (int s = 0; s < SEQ; ++s) {
    float* prow = xrow_base + (size_t)s * NHID;

    float4 acc[BPERG];
#pragma unroll
    for (int b = 0; b < BPERG; ++b) acc[b] = make_float4(0.f, 0.f, 0.f, 0.f);

    if (s > 0) {
      // Stage h_{s-1} (8 rows x 1024) into swizzled LDS: plain float4 loads
      // (L2-hit when co-located; MALL fill otherwise - agent copy is there).
      const float* base =
          xi + (size_t)(bg * BPERG) * SEQ * NHID + (size_t)(s - 1) * NHID + tid * 4;
#pragma unroll
      for (int b = 0; b < BPERG; ++b) {
        float4 v = *(const float4*)(base + (size_t)b * SEQ * NHID);
        *(float4*)&hs[b * NHID + ((tid * 4) ^ stswz)] = v;
      }
      __syncthreads();

      // Partial matvec over this thread's 32-k slice.
#pragma unroll
      for (int b = 0; b < BPERG; ++b) {
#pragma unroll
        for (int kq = 0; kq < 8; ++kq) {
          const float4 h4 =
              *(const float4*)&hs[b * NHID + kseg * 32 + ((kq * 4) ^ hswz)];
          FMA4(h4.x, w[kq * 4 + 0], acc[b]);
          FMA4(h4.y, w[kq * 4 + 1], acc[b]);
          FMA4(h4.z, w[kq * 4 + 2], acc[b]);
          FMA4(h4.w, w[kq * 4 + 3], acc[b]);
        }
      }
    }

    // Write partials to LDS (bank-swizzled), reduce 32-way per output.
    {
      const int u = kseg * 8 + c4;
      const int sw = (((kseg & 7) ^ c4)) << 2;
#pragma unroll
      for (int b = 0; b < BPERG; ++b)
        *(float4*)&P[u * 32 + ((b * 4) ^ sw)] = acc[b];
    }
    __syncthreads();

    float sum = 0.f;
#pragma unroll
    for (int q = 0; q < 32; ++q) {
      const int uu = q * 8 + oc4;
      const int sw2 = ((q & 7) ^ oc4) << 2;
      sum += P[uu * 32 + ((ob * 4 + oce) ^ sw2)];
    }

    // Activation + dual-store of h_s: agent (MALL truth) then plain (fast
    // local-L2 copy; plain-last so neither store is dead).
    const float hn = fmaxf(tanhf(xin + sum), 0.f);
    __hip_atomic_store(prow, hn, __ATOMIC_RELAXED, __HIP_MEMORY_SCOPE_AGENT);
    *prow = hn;

    // ---- group barrier: epoch flags, dual-stored ----
    // syncthreads drains vmcnt(0): both h stores are complete (MALL / L2)
    // before the flag stores issue.
    __syncthreads();
    const unsigned int target = (unsigned int)(s + 1);
    if (tid == 0) {
      __hip_atomic_store(myflag, target, __ATOMIC_RELAXED,
                         __HIP_MEMORY_SCOPE_AGENT);
      *myflag = target;
    }

    // Hoist next step's xin load: its MALL latency hides under the poll.
    if (s + 1 < SEQ)
      xin = __hip_atomic_load(xrow_base + (size_t)(s + 1) * NHID,
                              __ATOMIC_RELAXED, __HIP_MEMORY_SCOPE_AGENT);

    if (tid < 64) {
      // Wave 0 polls: lane j reads flag j (lanes 32-63 duplicate).
      // Fast path sc0 (L2); every 8th poll sc0+sc1 (MALL) so progress is
      // guaranteed regardless of block->XCD placement.
      int it = 0;
      while (true) {
        unsigned int v;
        if ((it++ & 7) == 7) {
          asm volatile(
              "global_load_dword %0, %1, off sc0 sc1\n\t"
              "s_waitcnt vmcnt(0)"
              : "=v"(v) : "v"(pollflag) : "memory");
        } else {
          asm volatile(
              "global_load_dword %0, %1, off sc0\n\t"
              "s_waitcnt vmcnt(0)"
              : "=v"(v) : "v"(pollflag) : "memory");
        }
        __builtin_amdgcn_sched_barrier(0);
        if (__all(v >= target)) break;
        __builtin_amdgcn_s_sleep(1);
      }
    }
    __syncthreads();
  }
}

extern "C" void kernel_launch(void* const* d_in, const int* in_sizes, int n_in,
                              void* d_out, int out_size, void* d_ws, size_t ws_size,
                              hipStream_t stream) {
  const float* x  = (const float*)d_in[0];  // [64,512,512]
  const float* Wi = (const float*)d_in[1];  // [512,1024]
  const float* bi = (const float*)d_in[2];  // [1024]
  const float* Wh = (const float*)d_in[3];  // [1024,1024]
  const float* Wo = (const float*)d_in[4];  // [1024,512]
  const float* bo = (const float*)d_in[5];  // [512]
  float* out = (float*)d_out;               // [64,512,512]
  float* xi  = (float*)d_ws;                // [64,512,1024] = 128 MB scratch

  // Epoch flags in d_out head (8 groups x 32 x 4B = 1KB);
  // overwritten by the final GEMM. Zeroed every launch.
  unsigned int* flags = (unsigned int*)d_out;

  const int M = BATCH * SEQ;  // 32768

  dim3 blk(256);
  hipMemsetAsync(flags, 0, GROUPS * BPG * sizeof(unsigned int), stream);
  // xi = x @ Wi + bi
  gemm_bias<<<dim3(NHID / BN, M / BM), blk, 0, stream>>>(x, Wi, bi, xi, M, NHID, NIN);
  // sequential scan (cooperative: all 256 blocks co-resident)
  {
    const float* Wh_p = Wh;
    float* xi_p = xi;
    unsigned int* flags_p = flags;
    void* args[3] = {(void*)&Wh_p, (void*)&xi_p, (void*)&flags_p};
    hipLaunchCooperativeKernel((const void*)rnn_scan_ws, dim3(GROUPS * BPG),
                               dim3(256), args, 0, stream);
  }
  // y = h @ Wo + bo
  gemm_bias<<<dim3(NOUT / BN, M / BM), blk, 0, stream>>>(xi, Wo, bo, out, M, NOUT, NHID);
}

// Round 9
// 2478.413 us; speedup vs baseline: 2.1890x; 2.1890x over previous
//
#include <hip/hip_runtime.h>
#include <math.h>

// Sizes (fixed by the problem)
#define BATCH   64
#define SEQ     512
#define NIN     512
#define NHID    1024
#define NOUT    512

typedef short short8 __attribute__((ext_vector_type(8)));
typedef float f32x4 __attribute__((ext_vector_type(4)));

// RNE fp32 -> bf16 bits
__device__ __forceinline__ unsigned short f2bf(float f) {
  unsigned int u = __float_as_uint(f);
  unsigned int r = (u + 0x7fffu + ((u >> 16) & 1u)) >> 16;
  return (unsigned short)r;
}

// ---------------- Tiled fp32 GEMM with bias (xi path; feeds the recurrence,
// stays full fp32): BM=128, BN=64, BK=16, 256 threads, 8x4 microtile.
#define BM 128
#define BN 64
#define BK 16

__global__ __launch_bounds__(256) void gemm_bias(
    const float* __restrict__ A, const float* __restrict__ B,
    const float* __restrict__ bias, float* __restrict__ C,
    int M, int N, int K) {
  __shared__ float As[BK][BM + 4];  // transposed A tile
  __shared__ float Bs[BK][BN + 4];

  const int tid = threadIdx.x;
  const int bx = blockIdx.x;  // N tile
  const int by = blockIdx.y;  // M tile

  const int tm = (tid / 16) * 8;   // 0..120, 8 rows
  const int tn = (tid % 16) * 4;   // 0..60, 4 cols

  const int ar = tid / 4;            // 0..63 (+64 second row)
  const int ac = (tid % 4) * 4;      // k 0,4,8,12
  const int br = tid / 16;           // 0..15
  const int bc = (tid % 16) * 4;     // 0..60

  float acc[8][4] = {};

  for (int k0 = 0; k0 < K; k0 += BK) {
    float4 av0 = *(const float4*)&A[(size_t)(by * BM + ar) * K + k0 + ac];
    float4 av1 = *(const float4*)&A[(size_t)(by * BM + ar + 64) * K + k0 + ac];
    As[ac + 0][ar] = av0.x;  As[ac + 0][ar + 64] = av1.x;
    As[ac + 1][ar] = av0.y;  As[ac + 1][ar + 64] = av1.y;
    As[ac + 2][ar] = av0.z;  As[ac + 2][ar + 64] = av1.z;
    As[ac + 3][ar] = av0.w;  As[ac + 3][ar + 64] = av1.w;
    float4 bv = *(const float4*)&B[(size_t)(k0 + br) * N + bx * BN + bc];
    *(float4*)&Bs[br][bc] = bv;
    __syncthreads();

#pragma unroll
    for (int k = 0; k < BK; ++k) {
      float4 a0 = *(const float4*)&As[k][tm];
      float4 a1 = *(const float4*)&As[k][tm + 4];
      float4 b4 = *(const float4*)&Bs[k][tn];
      float ae[8] = {a0.x, a0.y, a0.z, a0.w, a1.x, a1.y, a1.z, a1.w};
      float be[4] = {b4.x, b4.y, b4.z, b4.w};
#pragma unroll
      for (int i = 0; i < 8; ++i)
#pragma unroll
        for (int j = 0; j < 4; ++j)
          acc[i][j] = fmaf(ae[i], be[j], acc[i][j]);
    }
    __syncthreads();
  }

  const float4 bb = *(const float4*)&bias[bx * BN + tn];
#pragma unroll
  for (int i = 0; i < 8; ++i) {
    float4 o;
    o.x = acc[i][0] + bb.x;
    o.y = acc[i][1] + bb.y;
    o.z = acc[i][2] + bb.z;
    o.w = acc[i][3] + bb.w;
    *(float4*)&C[(size_t)(by * BM + tm + i) * N + bx * BN + tn] = o;
  }
}

// ---------------- bf16 MFMA GEMM with bias (output projection) ----------
// C[M,N] = A[M,K]@B[K,N] + bias. fp32 inputs converted RNE to bf16 on the
// fly; fp32 accumulate in MFMA. 128x128 tile, BK=32, 4 waves (2x2), each
// wave 64x64 via 4x4 mfma_f32_16x16x32_bf16. LDS tiles [*][40] padded
// (80B row stride -> fragment ds_read_b128 spreads across all 32 banks).
#define OBM 128
#define OBN 128
#define OBK 32
#define LDK 40

__global__ __launch_bounds__(256) void gemm_bias_bf16(
    const float* __restrict__ A, const float* __restrict__ B,
    const float* __restrict__ bias, float* __restrict__ C,
    int M, int N, int K) {
  __shared__ unsigned short Asb[OBM][LDK];  // A[r][k] bf16 bits
  __shared__ unsigned short Bsb[OBN][LDK];  // B^T [n][k] bf16 bits

  const int tid  = threadIdx.x;
  const int lane = tid & 63;
  const int wid  = tid >> 6;        // 0..3
  const int wm   = wid >> 1;        // wave row (0..1)
  const int wn   = wid & 1;         // wave col (0..1)
  const int bx   = blockIdx.x;      // N tile
  const int by   = blockIdx.y;      // M tile

  // A staging: thread -> row ar=tid>>1 (0..127), k start aks=(tid&1)*16
  const int ar  = tid >> 1;
  const int aks = (tid & 1) * 16;
  // B staging: thread -> k base bk4=(tid>>5)*4 (0..28), n base bn4=(tid&31)*4
  const int bk4 = (tid >> 5) * 4;
  const int bn4 = (tid & 31) * 4;

  const int l15 = lane & 15;
  const int lk8 = (lane >> 4) * 8;  // fragment k offset

  f32x4 acc[4][4];
#pragma unroll
  for (int i = 0; i < 4; ++i)
#pragma unroll
    for (int j = 0; j < 4; ++j) acc[i][j] = (f32x4){0.f, 0.f, 0.f, 0.f};

  for (int k0 = 0; k0 < K; k0 += OBK) {
    // ---- stage A (128x32 fp32 -> bf16) ----
    const float* Ap = &A[(size_t)(by * OBM + ar) * K + k0 + aks];
    float4 a0 = *(const float4*)(Ap + 0);
    float4 a1 = *(const float4*)(Ap + 4);
    float4 a2 = *(const float4*)(Ap + 8);
    float4 a3 = *(const float4*)(Ap + 12);
    unsigned short ta[16] = {
        f2bf(a0.x), f2bf(a0.y), f2bf(a0.z), f2bf(a0.w),
        f2bf(a1.x), f2bf(a1.y), f2bf(a1.z), f2bf(a1.w),
        f2bf(a2.x), f2bf(a2.y), f2bf(a2.z), f2bf(a2.w),
        f2bf(a3.x), f2bf(a3.y), f2bf(a3.z), f2bf(a3.w)};
    *(short8*)&Asb[ar][aks + 0] = *(short8*)&ta[0];
    *(short8*)&Asb[ar][aks + 8] = *(short8*)&ta[8];

    // ---- stage B (32x128 fp32 -> bf16, transposed to [n][k]) ----
#pragma unroll
    for (int kk = 0; kk < 4; ++kk) {
      float4 bv = *(const float4*)&B[(size_t)(k0 + bk4 + kk) * N + bx * OBN + bn4];
      Bsb[bn4 + 0][bk4 + kk] = f2bf(bv.x);
      Bsb[bn4 + 1][bk4 + kk] = f2bf(bv.y);
      Bsb[bn4 + 2][bk4 + kk] = f2bf(bv.z);
      Bsb[bn4 + 3][bk4 + kk] = f2bf(bv.w);
    }
    __syncthreads();

    // ---- MFMA: wave (wm,wn) computes 64x64 ----
    short8 afr[4], bfr[4];
#pragma unroll
    for (int t = 0; t < 4; ++t) {
      afr[t] = *(const short8*)&Asb[wm * 64 + t * 16 + l15][lk8];
      bfr[t] = *(const short8*)&Bsb[wn * 64 + t * 16 + l15][lk8];
    }
#pragma unroll
    for (int rt = 0; rt < 4; ++rt)
#pragma unroll
      for (int ct = 0; ct < 4; ++ct)
        acc[rt][ct] = __builtin_amdgcn_mfma_f32_16x16x32_bf16(
            afr[rt], bfr[ct], acc[rt][ct], 0, 0, 0);
    __syncthreads();
  }

  // ---- epilogue: C = acc + bias ----
#pragma unroll
  for (int rt = 0; rt < 4; ++rt) {
    const int row0 = by * OBM + wm * 64 + rt * 16 + (lane >> 4) * 4;
#pragma unroll
    for (int ct = 0; ct < 4; ++ct) {
      const int col = bx * OBN + wn * 64 + ct * 16 + l15;
      const float bb = bias[col];
#pragma unroll
      for (int i = 0; i < 4; ++i)
        C[(size_t)(row0 + i) * N + col] = acc[rt][ct][i] + bb;
    }
  }
}

// ---------------- Cooperative weight-stationary scan (r7, proven) --------
#define GROUPS 8
#define BPG    32
#define BPERG  8

#define FMA4(hv, wv4, accv)              \
  accv.x = fmaf(hv, wv4.x, accv.x);      \
  accv.y = fmaf(hv, wv4.y, accv.y);      \
  accv.z = fmaf(hv, wv4.z, accv.z);      \
  accv.w = fmaf(hv, wv4.w, accv.w);

__global__ __launch_bounds__(256, 1) void rnn_scan_ws(
    const float* __restrict__ Wh, float* __restrict__ xi,
    unsigned int* flags) {
  __shared__ float hs[BPERG * NHID];   // 32 KB staged h, XOR-swizzled on k
  __shared__ float P[256 * 32];        // 32 KB partial sums

  const int tid  = threadIdx.x;
  const int bg   = blockIdx.x & 7;    // XCD id under round-robin dispatch
  const int jc   = blockIdx.x >> 3;   // 0..31 column chunk (32 cols)
  const int c4   = tid & 7;
  const int kseg = tid >> 3;
  const int colbase = jc * 32 + c4 * 4;
  const int hswz  = (kseg & 7) << 2;
  const int stswz = ((tid >> 3) & 7) << 2;
  const int ob   = tid >> 5;
  const int ocol = tid & 31;
  const int oc4  = ocol >> 2;
  const int oce  = ocol & 3;

  float4 w[32];
#pragma unroll
  for (int kk = 0; kk < 32; ++kk)
    w[kk] = *(const float4*)&Wh[(size_t)(kseg * 32 + kk) * NHID + colbase];

  float* const xrow_base =
      xi + (size_t)(bg * BPERG + ob) * SEQ * NHID + jc * 32 + ocol;
  unsigned int* const gflags = flags + bg * 32;
  unsigned int* const myflag = gflags + jc;
  unsigned int* const pollflag = gflags + (tid & 31);

  for (int s = 0; s < SEQ; ++s) {
    float* prow = xrow_base + (size_t)s * NHID;
    const float xin = __hip_atomic_load(prow, __ATOMIC_RELAXED,
                                        __HIP_MEMORY_SCOPE_AGENT);

    float4 acc[BPERG];
#pragma unroll
    for (int b = 0; b < BPERG; ++b) acc[b] = make_float4(0.f, 0.f, 0.f, 0.f);

    if (s > 0) {
      const float* base =
          xi + (size_t)(bg * BPERG) * SEQ * NHID + (size_t)(s - 1) * NHID + tid * 4;
#pragma unroll
      for (int b = 0; b < BPERG; ++b) {
        float4 v = *(const float4*)(base + (size_t)b * SEQ * NHID);
        *(float4*)&hs[b * NHID + ((tid * 4) ^ stswz)] = v;
      }
      __syncthreads();

#pragma unroll
      for (int b = 0; b < BPERG; ++b) {
#pragma unroll
        for (int kq = 0; kq < 8; ++kq) {
          const float4 h4 =
              *(const float4*)&hs[b * NHID + kseg * 32 + ((kq * 4) ^ hswz)];
          FMA4(h4.x, w[kq * 4 + 0], acc[b]);
          FMA4(h4.y, w[kq * 4 + 1], acc[b]);
          FMA4(h4.z, w[kq * 4 + 2], acc[b]);
          FMA4(h4.w, w[kq * 4 + 3], acc[b]);
        }
      }
    }

    {
      const int u = kseg * 8 + c4;
      const int sw = (((kseg & 7) ^ c4)) << 2;
#pragma unroll
      for (int b = 0; b < BPERG; ++b)
        *(float4*)&P[u * 32 + ((b * 4) ^ sw)] = acc[b];
    }
    __syncthreads();

    float sum = 0.f;
#pragma unroll
    for (int q = 0; q < 32; ++q) {
      const int uu = q * 8 + oc4;
      const int sw2 = ((q & 7) ^ oc4) << 2;
      sum += P[uu * 32 + ((ob * 4 + oce) ^ sw2)];
    }

    const float hn = fmaxf(tanhf(xin + sum), 0.f);
    __hip_atomic_store(prow, hn, __ATOMIC_RELAXED, __HIP_MEMORY_SCOPE_AGENT);

    __syncthreads();
    const unsigned int target = (unsigned int)(s + 1);
    if (tid == 0)
      __hip_atomic_store(myflag, target, __ATOMIC_RELAXED,
                         __HIP_MEMORY_SCOPE_AGENT);
    if (tid < 64) {
      while (true) {
        unsigned int v = __hip_atomic_load(pollflag, __ATOMIC_RELAXED,
                                           __HIP_MEMORY_SCOPE_AGENT);
        if (__all(v >= target)) break;
        __builtin_amdgcn_s_sleep(1);
      }
    }
    __syncthreads();
  }
}

extern "C" void kernel_launch(void* const* d_in, const int* in_sizes, int n_in,
                              void* d_out, int out_size, void* d_ws, size_t ws_size,
                              hipStream_t stream) {
  const float* x  = (const float*)d_in[0];  // [64,512,512]
  const float* Wi = (const float*)d_in[1];  // [512,1024]
  const float* bi = (const float*)d_in[2];  // [1024]
  const float* Wh = (const float*)d_in[3];  // [1024,1024]
  const float* Wo = (const float*)d_in[4];  // [1024,512]
  const float* bo = (const float*)d_in[5];  // [512]
  float* out = (float*)d_out;               // [64,512,512]
  float* xi  = (float*)d_ws;                // [64,512,1024] = 128 MB scratch

  unsigned int* flags = (unsigned int*)d_out;

  const int M = BATCH * SEQ;  // 32768

  dim3 blk(256);
  hipMemsetAsync(flags, 0, GROUPS * BPG * sizeof(unsigned int), stream);
  // xi = x @ Wi + bi  (fp32 — feeds the recurrence)
  gemm_bias<<<dim3(NHID / BN, M / BM), blk, 0, stream>>>(x, Wi, bi, xi, M, NHID, NIN);
  // sequential scan (cooperative: all 256 blocks co-resident)
  {
    const float* Wh_p = Wh;
    float* xi_p = xi;
    unsigned int* flags_p = flags;
    void* args[3] = {(void*)&Wh_p, (void*)&xi_p, (void*)&flags_p};
    hipLaunchCooperativeKernel((const void*)rnn_scan_ws, dim3(GROUPS * BPG),
                               dim3(256), args, 0, stream);
  }
  // y = h @ Wo + bo  (bf16 MFMA, fp32 accumulate — no recurrence downstream)
  gemm_bias_bf16<<<dim3(NOUT / OBN, M / OBM), blk, 0, stream>>>(xi, Wo, bo, out,
                                                               M, NOUT, NHID);
}